// Round 2
// baseline (336.314 us; speedup 1.0000x reference)
//
#include <hip/hip_runtime.h>
#include <hip/hip_bf16.h>

#define B_ 4
#define D_ 2048
#define HWS 64
#define C_ 192
#define G_ 128
#define NODES (B_*D_)   // 8192

// ---------------- K1: spatial mean-pool + FC + LayerNorm ----------------
__global__ __launch_bounds__(192) void pool_fc_ln_kernel(
    const float* __restrict__ x, const float* __restrict__ W,
    const float* __restrict__ bias, const float* __restrict__ gam,
    const float* __restrict__ bet, float* __restrict__ nf)
{
    int u = blockIdx.x;            // 0..8191 (= b*2048 + t)
    int tid = threadIdx.x;         // 0..191
    __shared__ float feat[C_];
    __shared__ float red[4];
    __shared__ float stats[2];

    const float* xb = x + (size_t)u * (HWS * C_);
    float a0 = 0.f, a1 = 0.f, a2 = 0.f, a3 = 0.f;
    #pragma unroll
    for (int s = 0; s < HWS; s += 4) {
        a0 += xb[(s + 0) * C_ + tid];
        a1 += xb[(s + 1) * C_ + tid];
        a2 += xb[(s + 2) * C_ + tid];
        a3 += xb[(s + 3) * C_ + tid];
    }
    feat[tid] = (a0 + a1 + a2 + a3) * (1.0f / HWS);
    __syncthreads();

    float h = 0.f;
    if (tid < G_) {
        h = bias[tid];
        #pragma unroll 4
        for (int c = 0; c < C_; ++c) h += feat[c] * W[c * G_ + tid];
    }
    // LayerNorm over the 128 values held by threads 0..127 (waves 0 and 1)
    float s1 = (tid < G_) ? h : 0.f;
    float s2 = (tid < G_) ? h * h : 0.f;
    #pragma unroll
    for (int off = 32; off >= 1; off >>= 1) {
        s1 += __shfl_xor(s1, off, 64);
        s2 += __shfl_xor(s2, off, 64);
    }
    int wid = tid >> 6;
    if ((tid & 63) == 0 && wid < 2) { red[wid] = s1; red[2 + wid] = s2; }
    __syncthreads();
    if (tid == 0) {
        float S = red[0] + red[1];
        float SS = red[2] + red[3];
        float mu = S / G_;
        float var = SS / G_ - mu * mu;
        stats[0] = mu;
        stats[1] = 1.0f / sqrtf(var + 1e-5f);
    }
    __syncthreads();
    if (tid < G_) {
        float v = (h - stats[0]) * stats[1] * gam[tid] + bet[tid];
        nf[(size_t)u * G_ + tid] = v;
    }
}

// ---------------- generic 4-matrix GEMM: Y[r] = X @ W[r] (+bias) --------
struct Gemm4Args {
    const float* W[4];
    const float* Wadd0;     // if non-null, added element-wise to W[0]
    const float* bias[4];   // may be null
    float* Y[4];
};

__global__ __launch_bounds__(256) void gemm128_kernel(
    const float* __restrict__ X, Gemm4Args args)
{
    int r = blockIdx.y;
    int row0 = blockIdx.x * 64;
    int tid = threadIdx.x;
    __shared__ float xs[64][G_];

    {
        const float4* Xv = (const float4*)(X + (size_t)row0 * G_);
        float4* xsv = (float4*)&xs[0][0];
        #pragma unroll
        for (int i = 0; i < 8; ++i) xsv[tid + i * 256] = Xv[tid + i * 256];
    }
    __syncthreads();

    int tx = tid & 31;   // cols tx*4 .. tx*4+3
    int ty = tid >> 5;   // rows ty*8 .. ty*8+7
    const float4* Wv = (const float4*)args.W[r];
    const float4* Av = (const float4*)args.Wadd0;
    bool addw = (r == 0) && (Av != nullptr);

    float4 acc[8];
    #pragma unroll
    for (int i = 0; i < 8; ++i) acc[i] = make_float4(0.f, 0.f, 0.f, 0.f);

    for (int k4 = 0; k4 < G_ / 4; ++k4) {
        int k = k4 * 4;
        float4 w0 = Wv[(k + 0) * 32 + tx];
        float4 w1 = Wv[(k + 1) * 32 + tx];
        float4 w2 = Wv[(k + 2) * 32 + tx];
        float4 w3 = Wv[(k + 3) * 32 + tx];
        if (addw) {
            float4 c0 = Av[(k + 0) * 32 + tx];
            float4 c1 = Av[(k + 1) * 32 + tx];
            float4 c2 = Av[(k + 2) * 32 + tx];
            float4 c3 = Av[(k + 3) * 32 + tx];
            w0.x += c0.x; w0.y += c0.y; w0.z += c0.z; w0.w += c0.w;
            w1.x += c1.x; w1.y += c1.y; w1.z += c1.z; w1.w += c1.w;
            w2.x += c2.x; w2.y += c2.y; w2.z += c2.z; w2.w += c2.w;
            w3.x += c3.x; w3.y += c3.y; w3.z += c3.z; w3.w += c3.w;
        }
        #pragma unroll
        for (int i = 0; i < 8; ++i) {
            float4 xv = *(const float4*)&xs[ty * 8 + i][k];
            acc[i].x += xv.x * w0.x + xv.y * w1.x + xv.z * w2.x + xv.w * w3.x;
            acc[i].y += xv.x * w0.y + xv.y * w1.y + xv.z * w2.y + xv.w * w3.y;
            acc[i].z += xv.x * w0.z + xv.y * w1.z + xv.z * w2.z + xv.w * w3.z;
            acc[i].w += xv.x * w0.w + xv.y * w1.w + xv.z * w2.w + xv.w * w3.w;
        }
    }

    float4 bb = make_float4(0.f, 0.f, 0.f, 0.f);
    if (args.bias[r]) bb = ((const float4*)args.bias[r])[tx];
    float4* Yv = (float4*)(args.Y[r] + (size_t)row0 * G_);
    #pragma unroll
    for (int i = 0; i < 8; ++i) {
        float4 o = acc[i];
        o.x += bb.x; o.y += bb.y; o.z += bb.z; o.w += bb.w;
        Yv[(ty * 8 + i) * 32 + tx] = o;
    }
}

// ---------------- RGCN stencil aggregate (mean per relation) ------------
__global__ __launch_bounds__(256) void rgcn_stencil_kernel(
    const float* __restrict__ Y, const float* __restrict__ rb,
    float* __restrict__ out)
{
    int idx = blockIdx.x * 256 + threadIdx.x;   // node*128 + g
    int g = idx & (G_ - 1);
    int u = idx >> 7;
    int t = u & (D_ - 1);
    const float* Y0 = Y;
    const float* Y1 = Y + (size_t)NODES * G_;
    const float* Y2 = Y1 + (size_t)NODES * G_;
    const float* Y3 = Y2 + (size_t)NODES * G_;

    float acc = Y0[idx] + rb[g];

    float s = 0.f;
    #pragma unroll
    for (int o = 1; o <= 5; ++o) if (t + o < D_) s += Y1[idx + o * G_];
    int c1 = min(5, D_ - 1 - t);
    acc += s / (float)max(c1, 1);

    s = 0.f;
    #pragma unroll
    for (int o = 1; o <= 5; ++o) if (t - o >= 0) s += Y2[idx - o * G_];
    int c2 = min(5, t);
    acc += s / (float)max(c2, 1);

    s = 0.f; int c3 = 0;
    if (t >= 15)     { s += Y3[idx - 15 * G_]; c3++; }
    if (t + 15 < D_) { s += Y3[idx + 15 * G_]; c3++; }
    acc += s / (float)max(c3, 1);

    out[idx] = acc;
}

// ---------------- per-node 13-neighbor multi-head attention -------------
__global__ __launch_bounds__(128) void attn_kernel(
    const float* __restrict__ Q, const float* __restrict__ Kk,
    const float* __restrict__ V, const float* __restrict__ S,
    float* __restrict__ out2)
{
    int u = blockIdx.x;
    int b = u >> 11;
    int t = u & (D_ - 1);
    int j = threadIdx.x;               // channel = head*32 + dim
    const float invs = 0.17677669529663687f;  // 1/sqrt(32)

    int srcs[13];
    srcs[0] = t;
    #pragma unroll
    for (int o = 1; o <= 5; ++o) {
        srcs[o]     = (t + o < D_) ? (t + o) : -1;   // rel1 incoming
        srcs[5 + o] = (t - o >= 0) ? (t - o) : -1;   // rel2 incoming
    }
    srcs[11] = (t >= 15) ? (t - 15) : -1;            // rel3 incoming
    srcs[12] = (t + 15 < D_) ? (t + 15) : -1;

    float q = Q[(size_t)u * G_ + j];
    int base = b << 11;
    float lg[13], vv[13];
    #pragma unroll
    for (int n = 0; n < 13; ++n) {
        int sidx = srcs[n];
        float kk = 0.f, vx = 0.f;
        if (sidx >= 0) {
            size_t off = (size_t)(base + sidx) * G_ + j;
            kk = Kk[off];
            vx = V[off];
        }
        float p = q * kk;
        p += __shfl_xor(p, 16, 32);
        p += __shfl_xor(p, 8, 32);
        p += __shfl_xor(p, 4, 32);
        p += __shfl_xor(p, 2, 32);
        p += __shfl_xor(p, 1, 32);
        lg[n] = (sidx >= 0) ? p * invs : -1e30f;
        vv[n] = vx;
    }
    float m = lg[0];
    #pragma unroll
    for (int n = 1; n < 13; ++n) m = fmaxf(m, lg[n]);
    float den = 0.f, agg = 0.f;
    #pragma unroll
    for (int n = 0; n < 13; ++n) {
        float e = expf(lg[n] - m);
        den += e;
        agg += e * vv[n];
    }
    out2[(size_t)u * G_ + j] = agg / den + S[(size_t)u * G_ + j];
}

// ---------------- BatchNorm (per batch, over nodes) + leaky ReLU --------
// Output is ALWAYS fp32 (reference returns float32; d_out is float*).
__global__ __launch_bounds__(256) void bn_lrelu_kernel(
    const float* __restrict__ X, const float* __restrict__ gam,
    const float* __restrict__ bet, float* __restrict__ out)
{
    int bc = blockIdx.x;        // b*128 + c
    int b = bc >> 7;
    int c = bc & 127;
    int tid = threadIdx.x;
    const float* basep = X + (size_t)b * D_ * G_ + c;

    float v[8];
    float s = 0.f, ss = 0.f;
    #pragma unroll
    for (int i = 0; i < 8; ++i) {
        float xv = basep[(size_t)(tid + i * 256) * G_];
        v[i] = xv; s += xv; ss += xv * xv;
    }
    #pragma unroll
    for (int off = 32; off >= 1; off >>= 1) {
        s += __shfl_xor(s, off, 64);
        ss += __shfl_xor(ss, off, 64);
    }
    __shared__ float rs[4], rss[4], stats[2];
    int wid = tid >> 6;
    if ((tid & 63) == 0) { rs[wid] = s; rss[wid] = ss; }
    __syncthreads();
    if (tid == 0) {
        float S = rs[0] + rs[1] + rs[2] + rs[3];
        float SS = rss[0] + rss[1] + rss[2] + rss[3];
        float mu = S / D_;
        float var = SS / D_ - mu * mu;
        stats[0] = mu;
        stats[1] = 1.0f / sqrtf(var + 1e-5f);
    }
    __syncthreads();
    float mu = stats[0], inv = stats[1];
    float gg = gam[c], bb = bet[c];
    float* ob = out + (size_t)b * D_ * G_ + c;
    #pragma unroll
    for (int i = 0; i < 8; ++i) {
        float y = (v[i] - mu) * inv * gg + bb;
        y = (y > 0.f) ? y : 0.01f * y;
        ob[(size_t)(tid + i * 256) * G_] = y;
    }
}

extern "C" void kernel_launch(void* const* d_in, const int* in_sizes, int n_in,
                              void* d_out, int out_size, void* d_ws, size_t ws_size,
                              hipStream_t stream)
{
    (void)in_sizes; (void)n_in; (void)out_size; (void)ws_size;
    const float* x      = (const float*)d_in[0];
    // d_in[1] edge_index, d_in[2] edge_type: fixed stencil, unused
    const float* fe_w   = (const float*)d_in[3];
    const float* fe_b   = (const float*)d_in[4];
    const float* ln_g   = (const float*)d_in[5];
    const float* ln_b   = (const float*)d_in[6];
    const float* w_rel  = (const float*)d_in[7];   // [2][4][128][128]
    const float* w_root = (const float*)d_in[8];   // [2][128][128]
    const float* rgcn_b = (const float*)d_in[9];   // [2][128]
    const float* wq  = (const float*)d_in[10];
    const float* bq  = (const float*)d_in[11];
    const float* wk  = (const float*)d_in[12];
    const float* bk  = (const float*)d_in[13];
    const float* wv  = (const float*)d_in[14];
    const float* bv  = (const float*)d_in[15];
    const float* wsk = (const float*)d_in[16];
    const float* bsk = (const float*)d_in[17];
    const float* bn_g = (const float*)d_in[18];
    const float* bn_b = (const float*)d_in[19];

    float* ws   = (float*)d_ws;
    float* nf   = ws;                               // [8192][128]
    float* Y    = ws + (size_t)NODES * G_;          // 4 x [8192][128]
    float* out2 = Y + (size_t)4 * NODES * G_;       // [8192][128]

    pool_fc_ln_kernel<<<NODES, 192, 0, stream>>>(x, fe_w, fe_b, ln_g, ln_b, nf);

    for (int l = 0; l < 2; ++l) {
        Gemm4Args ga;
        for (int r = 0; r < 4; ++r) {
            ga.W[r]    = w_rel + ((size_t)l * 4 + r) * G_ * G_;
            ga.bias[r] = nullptr;
            ga.Y[r]    = Y + (size_t)r * NODES * G_;
        }
        ga.Wadd0 = w_root + (size_t)l * G_ * G_;
        gemm128_kernel<<<dim3(NODES / 64, 4), 256, 0, stream>>>(nf, ga);

        // stencil: nf1 overwrites nf slot (nf dead after the GEMM)
        rgcn_stencil_kernel<<<NODES * G_ / 256, 256, 0, stream>>>(Y, rgcn_b + l * G_, nf);

        Gemm4Args gb;
        gb.W[0] = wq  + (size_t)l * G_ * G_; gb.bias[0] = bq  + l * G_; gb.Y[0] = Y;
        gb.W[1] = wk  + (size_t)l * G_ * G_; gb.bias[1] = bk  + l * G_; gb.Y[1] = Y + (size_t)NODES * G_;
        gb.W[2] = wv  + (size_t)l * G_ * G_; gb.bias[2] = bv  + l * G_; gb.Y[2] = Y + (size_t)2 * NODES * G_;
        gb.W[3] = wsk + (size_t)l * G_ * G_; gb.bias[3] = bsk + l * G_; gb.Y[3] = Y + (size_t)3 * NODES * G_;
        gb.Wadd0 = nullptr;
        gemm128_kernel<<<dim3(NODES / 64, 4), 256, 0, stream>>>(nf, gb);

        attn_kernel<<<NODES, 128, 0, stream>>>(
            Y, Y + (size_t)NODES * G_, Y + (size_t)2 * NODES * G_,
            Y + (size_t)3 * NODES * G_, out2);

        bn_lrelu_kernel<<<B_ * G_, 256, 0, stream>>>(
            out2, bn_g + l * G_, bn_b + l * G_,
            (l == 0) ? nf : (float*)d_out);
    }
}

// Round 3
// 299.800 us; speedup vs baseline: 1.1218x; 1.1218x over previous
//
#include <hip/hip_runtime.h>
#include <hip/hip_bf16.h>

#define B_ 4
#define D_ 2048
#define HWS 64
#define C_ 192
#define G_ 128
#define NODES (B_*D_)   // 8192

// ---------------- K1: spatial mean-pool + FC + LayerNorm ----------------
// float4-vectorized pooling: thread (cg=tid%48, rg=tid/48) reads rows
// rg, rg+4, ... — each wave issues 1KB-contiguous loads.
__global__ __launch_bounds__(192) void pool_fc_ln_kernel(
    const float* __restrict__ x, const float* __restrict__ W,
    const float* __restrict__ bias, const float* __restrict__ gam,
    const float* __restrict__ bet, float* __restrict__ nf)
{
    int u = blockIdx.x;            // 0..8191 (= b*2048 + t)
    int tid = threadIdx.x;         // 0..191
    __shared__ float feat[C_];
    __shared__ float4 red4[4][48];
    __shared__ float red[4];
    __shared__ float stats[2];

    const float4* xb4 = (const float4*)(x + (size_t)u * (HWS * C_)); // 48 f4/row
    int cg = tid % 48;
    int rg = tid / 48;             // 0..3
    float4 a = make_float4(0.f, 0.f, 0.f, 0.f);
    #pragma unroll
    for (int s = 0; s < HWS; s += 4) {
        float4 v = xb4[(size_t)(s + rg) * 48 + cg];
        a.x += v.x; a.y += v.y; a.z += v.z; a.w += v.w;
    }
    red4[rg][cg] = a;
    __syncthreads();
    if (rg == 0) {   // threads 0..47 finalize 4 channels each
        float4 b0 = red4[0][cg], b1 = red4[1][cg], b2 = red4[2][cg], b3 = red4[3][cg];
        feat[cg * 4 + 0] = (b0.x + b1.x + b2.x + b3.x) * (1.0f / HWS);
        feat[cg * 4 + 1] = (b0.y + b1.y + b2.y + b3.y) * (1.0f / HWS);
        feat[cg * 4 + 2] = (b0.z + b1.z + b2.z + b3.z) * (1.0f / HWS);
        feat[cg * 4 + 3] = (b0.w + b1.w + b2.w + b3.w) * (1.0f / HWS);
    }
    __syncthreads();

    float h = 0.f;
    if (tid < G_) {
        h = bias[tid];
        #pragma unroll 4
        for (int c = 0; c < C_; ++c) h += feat[c] * W[c * G_ + tid];
    }
    // LayerNorm over the 128 values held by threads 0..127 (waves 0 and 1)
    float s1 = (tid < G_) ? h : 0.f;
    float s2 = (tid < G_) ? h * h : 0.f;
    #pragma unroll
    for (int off = 32; off >= 1; off >>= 1) {
        s1 += __shfl_xor(s1, off, 64);
        s2 += __shfl_xor(s2, off, 64);
    }
    int wid = tid >> 6;
    if ((tid & 63) == 0 && wid < 2) { red[wid] = s1; red[2 + wid] = s2; }
    __syncthreads();
    if (tid == 0) {
        float S = red[0] + red[1];
        float SS = red[2] + red[3];
        float mu = S / G_;
        float var = SS / G_ - mu * mu;
        stats[0] = mu;
        stats[1] = 1.0f / sqrtf(var + 1e-5f);
    }
    __syncthreads();
    if (tid < G_) {
        float v = (h - stats[0]) * stats[1] * gam[tid] + bet[tid];
        nf[(size_t)u * G_ + tid] = v;
    }
}

// ---------------- generic 4-matrix GEMM: Y[r] = X @ W[r] (+bias) --------
// 32-row tiles -> 1024 blocks -> 4 waves/SIMD occupancy.
struct Gemm4Args {
    const float* W[4];
    const float* Wadd0;     // if non-null, added element-wise to W[0]
    const float* bias[4];   // may be null
    float* Y[4];
};

__global__ __launch_bounds__(256) void gemm128_kernel(
    const float* __restrict__ X, Gemm4Args args)
{
    int r = blockIdx.y;
    int row0 = blockIdx.x * 32;
    int tid = threadIdx.x;
    __shared__ float xs[32][G_];

    {
        const float4* Xv = (const float4*)(X + (size_t)row0 * G_);
        float4* xsv = (float4*)&xs[0][0];
        #pragma unroll
        for (int i = 0; i < 4; ++i) xsv[tid + i * 256] = Xv[tid + i * 256];
    }
    __syncthreads();

    int tx = tid & 31;   // cols tx*4 .. tx*4+3
    int ty = tid >> 5;   // rows ty*4 .. ty*4+3
    const float4* Wv = (const float4*)args.W[r];
    const float4* Av = (const float4*)args.Wadd0;
    bool addw = (r == 0) && (Av != nullptr);

    float4 acc[4];
    #pragma unroll
    for (int i = 0; i < 4; ++i) acc[i] = make_float4(0.f, 0.f, 0.f, 0.f);

    for (int k4 = 0; k4 < G_ / 4; ++k4) {
        int k = k4 * 4;
        float4 w0 = Wv[(k + 0) * 32 + tx];
        float4 w1 = Wv[(k + 1) * 32 + tx];
        float4 w2 = Wv[(k + 2) * 32 + tx];
        float4 w3 = Wv[(k + 3) * 32 + tx];
        if (addw) {
            float4 c0 = Av[(k + 0) * 32 + tx];
            float4 c1 = Av[(k + 1) * 32 + tx];
            float4 c2 = Av[(k + 2) * 32 + tx];
            float4 c3 = Av[(k + 3) * 32 + tx];
            w0.x += c0.x; w0.y += c0.y; w0.z += c0.z; w0.w += c0.w;
            w1.x += c1.x; w1.y += c1.y; w1.z += c1.z; w1.w += c1.w;
            w2.x += c2.x; w2.y += c2.y; w2.z += c2.z; w2.w += c2.w;
            w3.x += c3.x; w3.y += c3.y; w3.z += c3.z; w3.w += c3.w;
        }
        #pragma unroll
        for (int i = 0; i < 4; ++i) {
            float4 xv = *(const float4*)&xs[ty * 4 + i][k];
            acc[i].x += xv.x * w0.x + xv.y * w1.x + xv.z * w2.x + xv.w * w3.x;
            acc[i].y += xv.x * w0.y + xv.y * w1.y + xv.z * w2.y + xv.w * w3.y;
            acc[i].z += xv.x * w0.z + xv.y * w1.z + xv.z * w2.z + xv.w * w3.z;
            acc[i].w += xv.x * w0.w + xv.y * w1.w + xv.z * w2.w + xv.w * w3.w;
        }
    }

    float4 bb = make_float4(0.f, 0.f, 0.f, 0.f);
    if (args.bias[r]) bb = ((const float4*)args.bias[r])[tx];
    float4* Yv = (float4*)(args.Y[r] + (size_t)row0 * G_);
    #pragma unroll
    for (int i = 0; i < 4; ++i) {
        float4 o = acc[i];
        o.x += bb.x; o.y += bb.y; o.z += bb.z; o.w += bb.w;
        Yv[(ty * 4 + i) * 32 + tx] = o;
    }
}

// ---------------- RGCN stencil aggregate (mean per relation) ------------
__global__ __launch_bounds__(256) void rgcn_stencil_kernel(
    const float* __restrict__ Y, const float* __restrict__ rb,
    float* __restrict__ out)
{
    int idx = blockIdx.x * 256 + threadIdx.x;   // node*128 + g
    int g = idx & (G_ - 1);
    int u = idx >> 7;
    int t = u & (D_ - 1);
    const float* Y0 = Y;
    const float* Y1 = Y + (size_t)NODES * G_;
    const float* Y2 = Y1 + (size_t)NODES * G_;
    const float* Y3 = Y2 + (size_t)NODES * G_;

    float acc = Y0[idx] + rb[g];

    float s = 0.f;
    #pragma unroll
    for (int o = 1; o <= 5; ++o) if (t + o < D_) s += Y1[idx + o * G_];
    int c1 = min(5, D_ - 1 - t);
    acc += s / (float)max(c1, 1);

    s = 0.f;
    #pragma unroll
    for (int o = 1; o <= 5; ++o) if (t - o >= 0) s += Y2[idx - o * G_];
    int c2 = min(5, t);
    acc += s / (float)max(c2, 1);

    s = 0.f; int c3 = 0;
    if (t >= 15)     { s += Y3[idx - 15 * G_]; c3++; }
    if (t + 15 < D_) { s += Y3[idx + 15 * G_]; c3++; }
    acc += s / (float)max(c3, 1);

    out[idx] = acc;
}

// ---------------- per-node 13-neighbor multi-head attention -------------
__global__ __launch_bounds__(128) void attn_kernel(
    const float* __restrict__ Q, const float* __restrict__ Kk,
    const float* __restrict__ V, const float* __restrict__ S,
    float* __restrict__ out2)
{
    int u = blockIdx.x;
    int b = u >> 11;
    int t = u & (D_ - 1);
    int j = threadIdx.x;               // channel = head*32 + dim
    const float invs = 0.17677669529663687f;  // 1/sqrt(32)

    int srcs[13];
    srcs[0] = t;
    #pragma unroll
    for (int o = 1; o <= 5; ++o) {
        srcs[o]     = (t + o < D_) ? (t + o) : -1;   // rel1 incoming
        srcs[5 + o] = (t - o >= 0) ? (t - o) : -1;   // rel2 incoming
    }
    srcs[11] = (t >= 15) ? (t - 15) : -1;            // rel3 incoming
    srcs[12] = (t + 15 < D_) ? (t + 15) : -1;

    float q = Q[(size_t)u * G_ + j];
    int base = b << 11;
    float lg[13], vv[13];
    #pragma unroll
    for (int n = 0; n < 13; ++n) {
        int sidx = srcs[n];
        float kk = 0.f, vx = 0.f;
        if (sidx >= 0) {
            size_t off = (size_t)(base + sidx) * G_ + j;
            kk = Kk[off];
            vx = V[off];
        }
        float p = q * kk;
        p += __shfl_xor(p, 16, 32);
        p += __shfl_xor(p, 8, 32);
        p += __shfl_xor(p, 4, 32);
        p += __shfl_xor(p, 2, 32);
        p += __shfl_xor(p, 1, 32);
        lg[n] = (sidx >= 0) ? p * invs : -1e30f;
        vv[n] = vx;
    }
    float m = lg[0];
    #pragma unroll
    for (int n = 1; n < 13; ++n) m = fmaxf(m, lg[n]);
    float den = 0.f, agg = 0.f;
    #pragma unroll
    for (int n = 0; n < 13; ++n) {
        float e = expf(lg[n] - m);
        den += e;
        agg += e * vv[n];
    }
    out2[(size_t)u * G_ + j] = agg / den + S[(size_t)u * G_ + j];
}

// ---------------- BatchNorm: phase 1 — coalesced partial sums -----------
// block (chunk, b): 64 rows x 128 ch; partials[b][chunk][0..127]=sum,
// [128..255]=sumsq.
__global__ __launch_bounds__(256) void bn_stats_kernel(
    const float* __restrict__ X, float* __restrict__ partials)
{
    int chunk = blockIdx.x;    // 0..31
    int b = blockIdx.y;        // 0..3
    int tid = threadIdx.x;
    const float4* base4 = (const float4*)(X + ((size_t)b * D_ + chunk * 64) * G_);

    float4 s = make_float4(0.f, 0.f, 0.f, 0.f);
    float4 ss = make_float4(0.f, 0.f, 0.f, 0.f);
    #pragma unroll
    for (int p = 0; p < 8; ++p) {
        float4 v = base4[p * 256 + tid];          // chan group = tid&31 (invariant)
        s.x += v.x; s.y += v.y; s.z += v.z; s.w += v.w;
        ss.x += v.x * v.x; ss.y += v.y * v.y; ss.z += v.z * v.z; ss.w += v.w * v.w;
    }
    __shared__ float4 rs[8][32], rss[8][32];
    rs[tid >> 5][tid & 31] = s;
    rss[tid >> 5][tid & 31] = ss;
    __syncthreads();
    if (tid < 32) {
        float4 S = make_float4(0.f, 0.f, 0.f, 0.f);
        float4 SS = make_float4(0.f, 0.f, 0.f, 0.f);
        #pragma unroll
        for (int j = 0; j < 8; ++j) {
            float4 a = rs[j][tid], c = rss[j][tid];
            S.x += a.x; S.y += a.y; S.z += a.z; S.w += a.w;
            SS.x += c.x; SS.y += c.y; SS.z += c.z; SS.w += c.w;
        }
        float4* P = (float4*)(partials + ((size_t)b * 32 + chunk) * 256);
        P[tid] = S;
        P[32 + tid] = SS;
    }
}

// ---------------- BatchNorm: phase 2 — stats + normalize + lReLU --------
__global__ __launch_bounds__(256) void bn_apply_kernel(
    const float* __restrict__ X, const float* __restrict__ partials,
    const float* __restrict__ gam, const float* __restrict__ bet,
    float* __restrict__ out)
{
    int chunk = blockIdx.x;
    int b = blockIdx.y;
    int tid = threadIdx.x;
    __shared__ float smu[G_], sinv[G_];
    if (tid < G_) {
        float s = 0.f, ss = 0.f;
        const float* P = partials + (size_t)b * 32 * 256;
        #pragma unroll 4
        for (int k = 0; k < 32; ++k) {
            s += P[k * 256 + tid];
            ss += P[k * 256 + G_ + tid];
        }
        float mu = s / D_;
        float var = ss / D_ - mu * mu;
        smu[tid] = mu;
        sinv[tid] = 1.0f / sqrtf(var + 1e-5f);
    }
    __syncthreads();

    const float4* base4 = (const float4*)(X + ((size_t)b * D_ + chunk * 64) * G_);
    float4* ob4 = (float4*)(out + ((size_t)b * D_ + chunk * 64) * G_);
    int c4 = (tid & 31) * 4;
    float m0 = smu[c4], m1 = smu[c4 + 1], m2 = smu[c4 + 2], m3 = smu[c4 + 3];
    float i0 = sinv[c4] * gam[c4],     i1 = sinv[c4 + 1] * gam[c4 + 1];
    float i2 = sinv[c4 + 2] * gam[c4 + 2], i3 = sinv[c4 + 3] * gam[c4 + 3];
    float b0 = bet[c4], b1 = bet[c4 + 1], b2 = bet[c4 + 2], b3 = bet[c4 + 3];
    #pragma unroll
    for (int p = 0; p < 8; ++p) {
        float4 v = base4[p * 256 + tid];
        float4 y;
        y.x = (v.x - m0) * i0 + b0;
        y.y = (v.y - m1) * i1 + b1;
        y.z = (v.z - m2) * i2 + b2;
        y.w = (v.w - m3) * i3 + b3;
        y.x = (y.x > 0.f) ? y.x : 0.01f * y.x;
        y.y = (y.y > 0.f) ? y.y : 0.01f * y.y;
        y.z = (y.z > 0.f) ? y.z : 0.01f * y.z;
        y.w = (y.w > 0.f) ? y.w : 0.01f * y.w;
        ob4[p * 256 + tid] = y;
    }
}

extern "C" void kernel_launch(void* const* d_in, const int* in_sizes, int n_in,
                              void* d_out, int out_size, void* d_ws, size_t ws_size,
                              hipStream_t stream)
{
    (void)in_sizes; (void)n_in; (void)out_size; (void)ws_size;
    const float* x      = (const float*)d_in[0];
    // d_in[1] edge_index, d_in[2] edge_type: fixed stencil, unused
    const float* fe_w   = (const float*)d_in[3];
    const float* fe_b   = (const float*)d_in[4];
    const float* ln_g   = (const float*)d_in[5];
    const float* ln_b   = (const float*)d_in[6];
    const float* w_rel  = (const float*)d_in[7];   // [2][4][128][128]
    const float* w_root = (const float*)d_in[8];   // [2][128][128]
    const float* rgcn_b = (const float*)d_in[9];   // [2][128]
    const float* wq  = (const float*)d_in[10];
    const float* bq  = (const float*)d_in[11];
    const float* wk  = (const float*)d_in[12];
    const float* bk  = (const float*)d_in[13];
    const float* wv  = (const float*)d_in[14];
    const float* bv  = (const float*)d_in[15];
    const float* wsk = (const float*)d_in[16];
    const float* bsk = (const float*)d_in[17];
    const float* bn_g = (const float*)d_in[18];
    const float* bn_b = (const float*)d_in[19];

    float* ws   = (float*)d_ws;
    float* nf   = ws;                               // [8192][128]
    float* Y    = ws + (size_t)NODES * G_;          // 4 x [8192][128]
    float* out2 = Y + (size_t)4 * NODES * G_;       // [8192][128]
    float* partials = out2 + (size_t)NODES * G_;    // [4][32][256]

    pool_fc_ln_kernel<<<NODES, 192, 0, stream>>>(x, fe_w, fe_b, ln_g, ln_b, nf);

    for (int l = 0; l < 2; ++l) {
        Gemm4Args ga;
        for (int r = 0; r < 4; ++r) {
            ga.W[r]    = w_rel + ((size_t)l * 4 + r) * G_ * G_;
            ga.bias[r] = nullptr;
            ga.Y[r]    = Y + (size_t)r * NODES * G_;
        }
        ga.Wadd0 = w_root + (size_t)l * G_ * G_;
        gemm128_kernel<<<dim3(NODES / 32, 4), 256, 0, stream>>>(nf, ga);

        // stencil: nf1 overwrites nf slot (nf dead after the GEMM)
        rgcn_stencil_kernel<<<NODES * G_ / 256, 256, 0, stream>>>(Y, rgcn_b + l * G_, nf);

        Gemm4Args gb;
        gb.W[0] = wq  + (size_t)l * G_ * G_; gb.bias[0] = bq  + l * G_; gb.Y[0] = Y;
        gb.W[1] = wk  + (size_t)l * G_ * G_; gb.bias[1] = bk  + l * G_; gb.Y[1] = Y + (size_t)NODES * G_;
        gb.W[2] = wv  + (size_t)l * G_ * G_; gb.bias[2] = bv  + l * G_; gb.Y[2] = Y + (size_t)2 * NODES * G_;
        gb.W[3] = wsk + (size_t)l * G_ * G_; gb.bias[3] = bsk + l * G_; gb.Y[3] = Y + (size_t)3 * NODES * G_;
        gb.Wadd0 = nullptr;
        gemm128_kernel<<<dim3(NODES / 32, 4), 256, 0, stream>>>(nf, gb);

        attn_kernel<<<NODES, 128, 0, stream>>>(
            Y, Y + (size_t)NODES * G_, Y + (size_t)2 * NODES * G_,
            Y + (size_t)3 * NODES * G_, out2);

        bn_stats_kernel<<<dim3(32, 4), 256, 0, stream>>>(out2, partials);
        bn_apply_kernel<<<dim3(32, 4), 256, 0, stream>>>(
            out2, partials, bn_g + l * G_, bn_b + l * G_,
            (l == 0) ? nf : (float*)d_out);
    }
}

// Round 4
// 254.358 us; speedup vs baseline: 1.3222x; 1.1787x over previous
//
#include <hip/hip_runtime.h>
#include <hip/hip_bf16.h>

#define B_ 4
#define D_ 2048
#define HWS 64
#define C_ 192
#define G_ 128
#define NODES (B_*D_)   // 8192

typedef short bf8_t  __attribute__((ext_vector_type(8)));   // 8 bf16 (4 VGPR)
typedef float f32x4_t __attribute__((ext_vector_type(4)));
typedef unsigned short us4_t __attribute__((ext_vector_type(4)));

__device__ inline unsigned short f2bf(float f) {
    unsigned int u = __builtin_bit_cast(unsigned int, f);
    unsigned int r = (u + 0x7fffu + ((u >> 16) & 1u)) >> 16;   // RNE
    return (unsigned short)r;
}

// ---------------- K0: weight conversion to bf16 WT[n][k] (+root fold) ---
struct WconvArgs {
    const float* src[16];
    const float* add[16];   // null or w_root slice (folded into slot 0)
};
__global__ __launch_bounds__(256) void wconv_kernel(WconvArgs a, unsigned short* __restrict__ dst)
{
    int m = blockIdx.y;
    int idx = blockIdx.x * 256 + threadIdx.x;   // n*128 + k
    int n = idx >> 7;
    int k = idx & 127;
    float v = a.src[m][k * G_ + n];
    if (a.add[m]) v += a.add[m][k * G_ + n];
    dst[(size_t)m * 16384 + idx] = f2bf(v);
}

// ---------------- K1: spatial mean-pool + FC + LayerNorm (-> bf16) ------
__global__ __launch_bounds__(192) void pool_fc_ln_kernel(
    const float* __restrict__ x, const float* __restrict__ W,
    const float* __restrict__ bias, const float* __restrict__ gam,
    const float* __restrict__ bet, unsigned short* __restrict__ nf)
{
    int u = blockIdx.x;            // 0..8191 (= b*2048 + t)
    int tid = threadIdx.x;         // 0..191
    __shared__ float feat[C_];
    __shared__ float4 red4[4][48];
    __shared__ float red[4];
    __shared__ float stats[2];

    const float4* xb4 = (const float4*)(x + (size_t)u * (HWS * C_)); // 48 f4/row
    int cg = tid % 48;
    int rg = tid / 48;             // 0..3
    float4 a = make_float4(0.f, 0.f, 0.f, 0.f);
    #pragma unroll
    for (int s = 0; s < HWS; s += 4) {
        float4 v = xb4[(size_t)(s + rg) * 48 + cg];
        a.x += v.x; a.y += v.y; a.z += v.z; a.w += v.w;
    }
    red4[rg][cg] = a;
    __syncthreads();
    if (rg == 0) {
        float4 b0 = red4[0][cg], b1 = red4[1][cg], b2 = red4[2][cg], b3 = red4[3][cg];
        feat[cg * 4 + 0] = (b0.x + b1.x + b2.x + b3.x) * (1.0f / HWS);
        feat[cg * 4 + 1] = (b0.y + b1.y + b2.y + b3.y) * (1.0f / HWS);
        feat[cg * 4 + 2] = (b0.z + b1.z + b2.z + b3.z) * (1.0f / HWS);
        feat[cg * 4 + 3] = (b0.w + b1.w + b2.w + b3.w) * (1.0f / HWS);
    }
    __syncthreads();

    float h = 0.f;
    if (tid < G_) {
        h = bias[tid];
        #pragma unroll 4
        for (int c = 0; c < C_; ++c) h += feat[c] * W[c * G_ + tid];
    }
    float s1 = (tid < G_) ? h : 0.f;
    float s2 = (tid < G_) ? h * h : 0.f;
    #pragma unroll
    for (int off = 32; off >= 1; off >>= 1) {
        s1 += __shfl_xor(s1, off, 64);
        s2 += __shfl_xor(s2, off, 64);
    }
    int wid = tid >> 6;
    if ((tid & 63) == 0 && wid < 2) { red[wid] = s1; red[2 + wid] = s2; }
    __syncthreads();
    if (tid == 0) {
        float S = red[0] + red[1];
        float SS = red[2] + red[3];
        float mu = S / G_;
        float var = SS / G_ - mu * mu;
        stats[0] = mu;
        stats[1] = 1.0f / sqrtf(var + 1e-5f);
    }
    __syncthreads();
    if (tid < G_) {
        float v = (h - stats[0]) * stats[1] * gam[tid] + bet[tid];
        nf[(size_t)u * G_ + tid] = f2bf(v);
    }
}

// ---------------- MFMA GEMM: Y[r] = A_bf16 @ WT[r]^T (+bias) ------------
// block: 256 thr (4 waves), 64 rows x 128 cols; r = blockIdx.y.
struct GemmMfmaArgs {
    const unsigned short* WT[4];   // [128 n][128 k] bf16
    const float* bias[4];          // null => no bias
    float* Y[4];
};

__global__ __launch_bounds__(256) void gemm_mfma_kernel(
    const unsigned short* __restrict__ A, GemmMfmaArgs args)
{
    int r = blockIdx.y;
    int row0 = blockIdx.x * 64;
    int tid = threadIdx.x;
    __shared__ bf8_t As8[1024];            // 16 KB, row stride 256 B
    char* As = (char*)As8;

    {   // stage A tile with XOR swizzle (byte ^= (row&7)<<4)
        int rowb = tid >> 4;               // 0..15
        int col8 = tid & 15;
        #pragma unroll
        for (int p = 0; p < 4; ++p) {
            int rr = p * 16 + rowb;
            int off = (rr * 256 + col8 * 16) ^ ((rr & 7) << 4);
            *(bf8_t*)(As + off) =
                *(const bf8_t*)(A + (size_t)(row0 + rr) * G_ + col8 * 8);
        }
    }
    __syncthreads();

    int l = tid & 63, wv = tid >> 6;
    int arow = wv * 16 + (l & 15);
    int kgrp = l >> 4;                     // 0..3
    bf8_t a[4];
    #pragma unroll
    for (int kc = 0; kc < 4; ++kc) {
        int off = (arow * 256 + kc * 64 + kgrp * 16) ^ ((arow & 7) << 4);
        a[kc] = *(const bf8_t*)(As + off);
    }

    const unsigned short* WTr = args.WT[r];
    f32x4_t acc[8];
    #pragma unroll
    for (int n = 0; n < 8; ++n) acc[n] = (f32x4_t){0.f, 0.f, 0.f, 0.f};

    #pragma unroll
    for (int n = 0; n < 8; ++n) {
        const unsigned short* bp = WTr + (size_t)(n * 16 + (l & 15)) * G_ + kgrp * 8;
        bf8_t b0 = *(const bf8_t*)(bp);
        bf8_t b1 = *(const bf8_t*)(bp + 32);
        bf8_t b2 = *(const bf8_t*)(bp + 64);
        bf8_t b3 = *(const bf8_t*)(bp + 96);
        acc[n] = __builtin_amdgcn_mfma_f32_16x16x32_bf16(a[0], b0, acc[n], 0, 0, 0);
        acc[n] = __builtin_amdgcn_mfma_f32_16x16x32_bf16(a[1], b1, acc[n], 0, 0, 0);
        acc[n] = __builtin_amdgcn_mfma_f32_16x16x32_bf16(a[2], b2, acc[n], 0, 0, 0);
        acc[n] = __builtin_amdgcn_mfma_f32_16x16x32_bf16(a[3], b3, acc[n], 0, 0, 0);
    }

    const float* bias = args.bias[r];
    float* Y = args.Y[r];
    int rbase = row0 + wv * 16 + kgrp * 4;
    #pragma unroll
    for (int n = 0; n < 8; ++n) {
        int col = n * 16 + (l & 15);
        float bb = bias ? bias[col] : 0.f;
        #pragma unroll
        for (int j = 0; j < 4; ++j)
            Y[(size_t)(rbase + j) * G_ + col] = acc[n][j] + bb;
    }
}

// ---------------- RGCN stencil aggregate (mean per relation, -> bf16) ---
__global__ __launch_bounds__(256) void rgcn_stencil_kernel(
    const float* __restrict__ Y, const float* __restrict__ rb,
    unsigned short* __restrict__ out)
{
    int idx = blockIdx.x * 256 + threadIdx.x;   // node*128 + g
    int g = idx & (G_ - 1);
    int u = idx >> 7;
    int t = u & (D_ - 1);
    const float* Y0 = Y;
    const float* Y1 = Y + (size_t)NODES * G_;
    const float* Y2 = Y1 + (size_t)NODES * G_;
    const float* Y3 = Y2 + (size_t)NODES * G_;

    float acc = Y0[idx] + rb[g];

    float s = 0.f;
    #pragma unroll
    for (int o = 1; o <= 5; ++o) if (t + o < D_) s += Y1[idx + o * G_];
    int c1 = min(5, D_ - 1 - t);
    acc += s / (float)max(c1, 1);

    s = 0.f;
    #pragma unroll
    for (int o = 1; o <= 5; ++o) if (t - o >= 0) s += Y2[idx - o * G_];
    int c2 = min(5, t);
    acc += s / (float)max(c2, 1);

    s = 0.f; int c3 = 0;
    if (t >= 15)     { s += Y3[idx - 15 * G_]; c3++; }
    if (t + 15 < D_) { s += Y3[idx + 15 * G_]; c3++; }
    acc += s / (float)max(c3, 1);

    out[idx] = f2bf(acc);
}

// ---------------- per-node 13-neighbor multi-head attention -------------
__global__ __launch_bounds__(128) void attn_kernel(
    const float* __restrict__ Q, const float* __restrict__ Kk,
    const float* __restrict__ V, const float* __restrict__ S,
    float* __restrict__ out2)
{
    int u = blockIdx.x;
    int b = u >> 11;
    int t = u & (D_ - 1);
    int j = threadIdx.x;               // channel = head*32 + dim
    const float invs = 0.17677669529663687f;  // 1/sqrt(32)

    int srcs[13];
    srcs[0] = t;
    #pragma unroll
    for (int o = 1; o <= 5; ++o) {
        srcs[o]     = (t + o < D_) ? (t + o) : -1;   // rel1 incoming
        srcs[5 + o] = (t - o >= 0) ? (t - o) : -1;   // rel2 incoming
    }
    srcs[11] = (t >= 15) ? (t - 15) : -1;            // rel3 incoming
    srcs[12] = (t + 15 < D_) ? (t + 15) : -1;

    float q = Q[(size_t)u * G_ + j];
    int base = b << 11;
    float lg[13], vv[13];
    #pragma unroll
    for (int n = 0; n < 13; ++n) {
        int sidx = srcs[n];
        float kk = 0.f, vx = 0.f;
        if (sidx >= 0) {
            size_t off = (size_t)(base + sidx) * G_ + j;
            kk = Kk[off];
            vx = V[off];
        }
        float p = q * kk;
        p += __shfl_xor(p, 16, 32);
        p += __shfl_xor(p, 8, 32);
        p += __shfl_xor(p, 4, 32);
        p += __shfl_xor(p, 2, 32);
        p += __shfl_xor(p, 1, 32);
        lg[n] = (sidx >= 0) ? p * invs : -1e30f;
        vv[n] = vx;
    }
    float m = lg[0];
    #pragma unroll
    for (int n = 1; n < 13; ++n) m = fmaxf(m, lg[n]);
    float den = 0.f, agg = 0.f;
    #pragma unroll
    for (int n = 0; n < 13; ++n) {
        float e = expf(lg[n] - m);
        den += e;
        agg += e * vv[n];
    }
    out2[(size_t)u * G_ + j] = agg / den + S[(size_t)u * G_ + j];
}

// ---------------- BatchNorm: phase 1 — coalesced partial sums -----------
__global__ __launch_bounds__(256) void bn_stats_kernel(
    const float* __restrict__ X, float* __restrict__ partials)
{
    int chunk = blockIdx.x;    // 0..31
    int b = blockIdx.y;        // 0..3
    int tid = threadIdx.x;
    const float4* base4 = (const float4*)(X + ((size_t)b * D_ + chunk * 64) * G_);

    float4 s = make_float4(0.f, 0.f, 0.f, 0.f);
    float4 ss = make_float4(0.f, 0.f, 0.f, 0.f);
    #pragma unroll
    for (int p = 0; p < 8; ++p) {
        float4 v = base4[p * 256 + tid];
        s.x += v.x; s.y += v.y; s.z += v.z; s.w += v.w;
        ss.x += v.x * v.x; ss.y += v.y * v.y; ss.z += v.z * v.z; ss.w += v.w * v.w;
    }
    __shared__ float4 rs[8][32], rss[8][32];
    rs[tid >> 5][tid & 31] = s;
    rss[tid >> 5][tid & 31] = ss;
    __syncthreads();
    if (tid < 32) {
        float4 S = make_float4(0.f, 0.f, 0.f, 0.f);
        float4 SS = make_float4(0.f, 0.f, 0.f, 0.f);
        #pragma unroll
        for (int j = 0; j < 8; ++j) {
            float4 a = rs[j][tid], c = rss[j][tid];
            S.x += a.x; S.y += a.y; S.z += a.z; S.w += a.w;
            SS.x += c.x; SS.y += c.y; SS.z += c.z; SS.w += c.w;
        }
        float4* P = (float4*)(partials + ((size_t)b * 32 + chunk) * 256);
        P[tid] = S;
        P[32 + tid] = SS;
    }
}

// ---------------- BatchNorm: phase 2 — stats + normalize + lReLU --------
// BF=true -> write bf16 (feeds next layer's GEMM); else fp32 (d_out).
template <bool BF>
__global__ __launch_bounds__(256) void bn_apply_kernel(
    const float* __restrict__ X, const float* __restrict__ partials,
    const float* __restrict__ gam, const float* __restrict__ bet,
    void* __restrict__ outp)
{
    int chunk = blockIdx.x;
    int b = blockIdx.y;
    int tid = threadIdx.x;
    __shared__ float smu[G_], sinv[G_];
    if (tid < G_) {
        float s = 0.f, ss = 0.f;
        const float* P = partials + (size_t)b * 32 * 256;
        #pragma unroll 4
        for (int k = 0; k < 32; ++k) {
            s += P[k * 256 + tid];
            ss += P[k * 256 + G_ + tid];
        }
        float mu = s / D_;
        float var = ss / D_ - mu * mu;
        smu[tid] = mu;
        sinv[tid] = 1.0f / sqrtf(var + 1e-5f);
    }
    __syncthreads();

    const float4* base4 = (const float4*)(X + ((size_t)b * D_ + chunk * 64) * G_);
    int c4 = (tid & 31) * 4;
    float m0 = smu[c4], m1 = smu[c4 + 1], m2 = smu[c4 + 2], m3 = smu[c4 + 3];
    float i0 = sinv[c4] * gam[c4],     i1 = sinv[c4 + 1] * gam[c4 + 1];
    float i2 = sinv[c4 + 2] * gam[c4 + 2], i3 = sinv[c4 + 3] * gam[c4 + 3];
    float b0 = bet[c4], b1 = bet[c4 + 1], b2 = bet[c4 + 2], b3 = bet[c4 + 3];
    #pragma unroll
    for (int p = 0; p < 8; ++p) {
        float4 v = base4[p * 256 + tid];
        float4 y;
        y.x = (v.x - m0) * i0 + b0;
        y.y = (v.y - m1) * i1 + b1;
        y.z = (v.z - m2) * i2 + b2;
        y.w = (v.w - m3) * i3 + b3;
        y.x = (y.x > 0.f) ? y.x : 0.01f * y.x;
        y.y = (y.y > 0.f) ? y.y : 0.01f * y.y;
        y.z = (y.z > 0.f) ? y.z : 0.01f * y.z;
        y.w = (y.w > 0.f) ? y.w : 0.01f * y.w;
        if constexpr (BF) {
            us4_t o;
            o[0] = f2bf(y.x); o[1] = f2bf(y.y); o[2] = f2bf(y.z); o[3] = f2bf(y.w);
            us4_t* ob = (us4_t*)((unsigned short*)outp + ((size_t)b * D_ + chunk * 64) * G_);
            ob[p * 256 + tid] = o;
        } else {
            float4* ob = (float4*)((float*)outp + ((size_t)b * D_ + chunk * 64) * G_);
            ob[p * 256 + tid] = y;
        }
    }
}

extern "C" void kernel_launch(void* const* d_in, const int* in_sizes, int n_in,
                              void* d_out, int out_size, void* d_ws, size_t ws_size,
                              hipStream_t stream)
{
    (void)in_sizes; (void)n_in; (void)out_size; (void)ws_size;
    const float* x      = (const float*)d_in[0];
    const float* fe_w   = (const float*)d_in[3];
    const float* fe_b   = (const float*)d_in[4];
    const float* ln_g   = (const float*)d_in[5];
    const float* ln_b   = (const float*)d_in[6];
    const float* w_rel  = (const float*)d_in[7];   // [2][4][128][128]
    const float* w_root = (const float*)d_in[8];   // [2][128][128]
    const float* rgcn_b = (const float*)d_in[9];   // [2][128]
    const float* wq  = (const float*)d_in[10];
    const float* bq  = (const float*)d_in[11];
    const float* wk  = (const float*)d_in[12];
    const float* bk  = (const float*)d_in[13];
    const float* wv  = (const float*)d_in[14];
    const float* bv  = (const float*)d_in[15];
    const float* wsk = (const float*)d_in[16];
    const float* bsk = (const float*)d_in[17];
    const float* bn_g = (const float*)d_in[18];
    const float* bn_b = (const float*)d_in[19];

    float* ws   = (float*)d_ws;
    float* Y    = ws;                                // 4 x [8192][128] f32
    float* out2 = Y + (size_t)4 * NODES * G_;        // [8192][128] f32
    float* partials = out2 + (size_t)NODES * G_;     // [4][32][256] f32
    unsigned short* nf_bf = (unsigned short*)(partials + 4 * 32 * 256); // [8192][128] bf16
    unsigned short* wbf   = nf_bf + (size_t)NODES * G_;                 // 16 x [128][128] bf16

    // ---- weight conversion (bf16, transposed, root folded into rel0) ----
    WconvArgs wa;
    for (int l = 0; l < 2; ++l) {
        for (int r = 0; r < 4; ++r) {
            wa.src[l * 8 + r] = w_rel + ((size_t)l * 4 + r) * G_ * G_;
            wa.add[l * 8 + r] = (r == 0) ? (w_root + (size_t)l * G_ * G_) : nullptr;
        }
        wa.src[l * 8 + 4] = wq  + (size_t)l * G_ * G_; wa.add[l * 8 + 4] = nullptr;
        wa.src[l * 8 + 5] = wk  + (size_t)l * G_ * G_; wa.add[l * 8 + 5] = nullptr;
        wa.src[l * 8 + 6] = wv  + (size_t)l * G_ * G_; wa.add[l * 8 + 6] = nullptr;
        wa.src[l * 8 + 7] = wsk + (size_t)l * G_ * G_; wa.add[l * 8 + 7] = nullptr;
    }
    wconv_kernel<<<dim3(64, 16), 256, 0, stream>>>(wa, wbf);

    pool_fc_ln_kernel<<<NODES, 192, 0, stream>>>(x, fe_w, fe_b, ln_g, ln_b, nf_bf);

    for (int l = 0; l < 2; ++l) {
        GemmMfmaArgs ga;
        for (int r = 0; r < 4; ++r) {
            ga.WT[r]   = wbf + (size_t)(l * 8 + r) * 16384;
            ga.bias[r] = nullptr;
            ga.Y[r]    = Y + (size_t)r * NODES * G_;
        }
        gemm_mfma_kernel<<<dim3(NODES / 64, 4), 256, 0, stream>>>(nf_bf, ga);

        rgcn_stencil_kernel<<<NODES * G_ / 256, 256, 0, stream>>>(Y, rgcn_b + l * G_, nf_bf);

        GemmMfmaArgs gb;
        gb.WT[0] = wbf + (size_t)(l * 8 + 4) * 16384; gb.bias[0] = bq  + l * G_; gb.Y[0] = Y;
        gb.WT[1] = wbf + (size_t)(l * 8 + 5) * 16384; gb.bias[1] = bk  + l * G_; gb.Y[1] = Y + (size_t)NODES * G_;
        gb.WT[2] = wbf + (size_t)(l * 8 + 6) * 16384; gb.bias[2] = bv  + l * G_; gb.Y[2] = Y + (size_t)2 * NODES * G_;
        gb.WT[3] = wbf + (size_t)(l * 8 + 7) * 16384; gb.bias[3] = bsk + l * G_; gb.Y[3] = Y + (size_t)3 * NODES * G_;
        gemm_mfma_kernel<<<dim3(NODES / 64, 4), 256, 0, stream>>>(nf_bf, gb);

        attn_kernel<<<NODES, 128, 0, stream>>>(
            Y, Y + (size_t)NODES * G_, Y + (size_t)2 * NODES * G_,
            Y + (size_t)3 * NODES * G_, out2);

        bn_stats_kernel<<<dim3(32, 4), 256, 0, stream>>>(out2, partials);
        if (l == 0) {
            bn_apply_kernel<true><<<dim3(32, 4), 256, 0, stream>>>(
                out2, partials, bn_g, bn_b, nf_bf);
        } else {
            bn_apply_kernel<false><<<dim3(32, 4), 256, 0, stream>>>(
                out2, partials, bn_g + G_, bn_b + G_, d_out);
        }
    }
}